// Round 11
// baseline (154.218 us; speedup 1.0000x reference)
//
#include <hip/hip_runtime.h>
#include <cstdio>

// ---------------------------------------------------------------------------
// MemoryEfficientRGBDecoderStem — algebraic reduction + fused bf16 MFMA.
//   GEMM1 K collapses 1156 -> 137 (pad 144): gestalt spatially constant
//   (per-batch Wg), cos embeddings separable in h/w, bias1 folded into the
//   k=136 column (input-side frag carries 1.0 there).
//   R17 = R12 k_main (verified best: k_main 67.1 µs, total 149.9-150.7) +
//   4-BATCHED k_pre B1F: each block builds 4 consecutive n sharing one
//   gestT staging (gestalt L2 traffic 4x down, psum LDS reads 8->5 per
//   4-n unit, grid 1408->640). Accumulation order per n unchanged ->
//   bit-identical numerics. Targets the stable ~83 µs non-k_main gap.
//   k_main: 8-wave block, NSTAGE=6, barrier every 2nd chunk, ANTI-PHASE
//   wave groups (SIMD k hosts waves {k,k+4}: one issues MFMA cluster while
//   partner issues silu VALU), B1FS/B1FB dedup, XCD-bijective swizzle.
// ---------------------------------------------------------------------------

#define NFREQ 16
#define BB 16
#define G 256
#define KIN 1156
#define K1 144
#define STAGE_U16 12800   // 25600 B per stage: af 9216 B + wf 16384 B
#define NSTAGE 6

typedef unsigned short u16;
using bf16x8 = __bf16 __attribute__((ext_vector_type(8)));
using f32x16 = float __attribute__((ext_vector_type(16)));
using f32x4  = float __attribute__((ext_vector_type(4)));

__device__ __forceinline__ u16 f2bf(float f) {          // RNE (for weights)
  unsigned u = __float_as_uint(f);
  u += 0x7fffu + ((u >> 16) & 1u);
  return (u16)(u >> 16);
}
__device__ __forceinline__ unsigned pk2(float a, float b) {  // RNE pair
  return (unsigned)f2bf(a) | ((unsigned)f2bf(b) << 16);
}
// fast pair pack, round-half-up: 2x v_add + v_perm_b32
__device__ __forceinline__ unsigned pk2f(float a, float b) {
  unsigned ua = __float_as_uint(a) + 0x8000u;
  unsigned ub = __float_as_uint(b) + 0x8000u;
  return __builtin_amdgcn_perm(ub, ua, 0x07060302u);  // {ub.hi16, ua.hi16}
}
// fast silu: v_mul + v_exp_f32 + v_add + v_rcp_f32 + v_mul
__device__ __forceinline__ float silu(float h) {
  float e = __builtin_amdgcn_exp2f(h * -1.44269504088896f);
  return h * __builtin_amdgcn_rcpf(1.f + e);
}
// async global->LDS DMA: per-lane g addr, wave-uniform LDS base; lane i -> l + 16*i
__device__ __forceinline__ void gl_lds16(const u16* g, u16* l) {
  __builtin_amdgcn_global_load_lds(
      (const __attribute__((address_space(1))) void*)g,
      (__attribute__((address_space(3))) void*)l, 16, 0, 0);
}

// --------------------------- fused prologue --------------------------------
// blocks [0,256): B1FS/B1FB build, 4 n per block | [256,384): W2F pack |
// [384,640): cos tables
__global__ void k_pre(const float* __restrict__ pos,
                      const float* __restrict__ gestalt,
                      const float* __restrict__ w1,
                      const float* __restrict__ w2,
                      const float* __restrict__ bias1,
                      float* __restrict__ cosx, float* __restrict__ cosy,
                      u16* __restrict__ B1FS, u16* __restrict__ B1FB,
                      u16* __restrict__ W2F) {
  const int bid = blockIdx.x;
  const int t = threadIdx.x;

  if (bid < 256) {
    // ---- per-batch reduced W1 for n = bid*4 .. bid*4+3, shared gestT ----
    __shared__ float w1r[4][KIN];     // 18.5 KB
    __shared__ float gestT[G * 17];   // [c][bb], pitch 17: conflict-free R/W
    __shared__ float psum[4][256];
    __shared__ float wg[4][64];
    const int n0 = bid * 4;
#pragma unroll
    for (int s = 0; s < 4; ++s)
      for (int i = t; i < KIN; i += 256) w1r[s][i] = w1[(size_t)(n0 + s) * KIN + i];
    for (int i = t; i < BB * G; i += 256) {
      int bb = i >> 8, c = i & 255;
      gestT[c * 17 + bb] = gestalt[i];
    }
    __syncthreads();
    {
      // Wg[s][bb][j] = sum_c gestalt[bb][c]*w1[n0+s][4c+j]; t = q*64+j*16+bb
      // Per-n accumulation order identical to the 1-n version -> bit-exact.
      int bb = t & 15, j = (t >> 4) & 3, q = t >> 6;
      float a0 = 0.f, a1 = 0.f, a2 = 0.f, a3 = 0.f;
#pragma unroll 8
      for (int c = q * 64; c < q * 64 + 64; ++c) {
        float g = gestT[c * 17 + bb];
        a0 += g * w1r[0][4 * c + j];
        a1 += g * w1r[1][4 * c + j];
        a2 += g * w1r[2][4 * c + j];
        a3 += g * w1r[3][4 * c + j];
      }
      psum[0][t] = a0; psum[1][t] = a1; psum[2][t] = a2; psum[3][t] = a3;
    }
    __syncthreads();
    if (t < 64) {
      int bb = t >> 2, j = t & 3;
#pragma unroll
      for (int s = 0; s < 4; ++s)
        wg[s][t] = psum[s][j * 16 + bb] + psum[s][64 + j * 16 + bb] +
                   psum[s][128 + j * 16 + bb] + psum[s][192 + j * 16 + bb];
    }
    __syncthreads();
    // 4 n x 48 chunks: {kc 0..15, bb=0 shared} -> B1FS ; {kc 16,17 x bb} -> B1FB
    if (t < 192) {
      const int s = t / 48, tt = t - s * 48;
      const int n = n0 + s;
      const float b1v = bias1[n];     // folded into k=136 column
      const int ch = n >> 5, l31n = n & 31;
      int bb, kc;
      if (tt < 16) { bb = 0; kc = tt; }
      else         { bb = (tt - 16) >> 1; kc = 16 + ((tt - 16) & 1); }
      int k0 = kc * 8;
      float v[8];
#pragma unroll
      for (int i = 0; i < 8; ++i) {
        int k = k0 + i;
        float vv;
        if (k < 64)       vv = w1r[s][1024 + 8 * (k >> 2) + (k & 3)];
        else if (k < 128) { int kk = k - 64; vv = w1r[s][1024 + 8 * (kk >> 2) + 4 + (kk & 3)]; }
        else if (k < 132) vv = wg[s][bb * 4 + (k - 128)];
        else if (k < 136) vv = w1r[s][1152 + (k - 132)];
        else if (k == 136) vv = b1v;   // bias column
        else              vv = 0.f;
        v[i] = vv;
      }
      uint4 u;
      u.x = pk2(v[0], v[1]); u.y = pk2(v[2], v[3]);
      u.z = pk2(v[4], v[5]); u.w = pk2(v[6], v[7]);
      if (kc < 16) {
        size_t idx0 = (((size_t)ch * 8 + (kc >> 1)) * 64 + (kc & 1) * 32 + l31n) * 8;
        *(uint4*)(B1FS + idx0) = u;
      } else {
        size_t idx0 = (((size_t)bb * 32 + ch) * 64 + (kc - 16) * 32 + l31n) * 8;
        *(uint4*)(B1FB + idx0) = u;
      }
    }
  } else if (bid < 384) {
    // ---- W2F: frag-contiguous bf16; 8 u16 per thread, uint4 store ----
    int e8 = (bid - 256) * 256 + t;     // 0..32767
    int lane = e8 & 63;
    int ct   = (e8 >> 6) & 7;
    int kc   = e8 >> 9;
    int n2 = ct * 32 + (lane & 31);
    int k2 = kc * 16 + (lane >> 5) * 8;
    const float* src = w2 + (size_t)n2 * 1024 + k2;
    uint4 u;
    u.x = pk2(src[0], src[1]); u.y = pk2(src[2], src[3]);
    u.z = pk2(src[4], src[5]); u.w = pk2(src[6], src[7]);
    *(uint4*)(W2F + (size_t)e8 * 8) = u;
  } else {
    // ---- cos tables (exact fp32 op-order of reference) ----
    int idx = (bid - 384) * 256 + t;    // 0..65535
    int table = idx >> 15;
    int rem = idx & 32767;
    int b = rem >> 11;
    int f = (rem >> 7) & 15;
    int c = rem & 127;
    float p0 = pos[b * 4 + 0];
    float p1 = pos[b * 4 + 1];
    float p3 = pos[b * 4 + 3];
    float x = fminf(fmaxf(p0, -1.f), 1.f);
    float y = fminf(fmaxf(p1, -1.f), 1.f);
    float stdv = 0.1f / fminf(fmaxf(p3, 0.0078125f), 0.5f);  // min_std = 1/128
    const float half_pi = 1.57079632679489661923f;
    float g = ((float)c / 127.0f) * 2.0f - 1.0f;
    float ng = (table == 0) ? ((g - x) * stdv) * half_pi     // std_x = std (W/H=1)
                            : ((g - y) * stdv) * half_pi;
    float freq = (float)(1 << f);
    float val = cosf(ng * freq);
    if (table == 0) cosx[(b * NFREQ + f) * 128 + c] = val;
    else            cosy[(b * NFREQ + f) * 128 + c] = val;
  }
}

// ----------------------- main-kernel compute helpers -----------------------

__device__ __forceinline__ f32x16 mfma_bf16(bf16x8 a, bf16x8 b, f32x16 c) {
  return __builtin_amdgcn_mfma_f32_32x32x16_bf16(a, b, c, 0, 0, 0);
}

// GEMM1: 9 MFMA, two independent chains, C-input = hoisted ZERO
__device__ __forceinline__ void gemm1(const u16* afb, const bf16x8* bfr, int lane8,
                                      const f32x16& ZERO, f32x16& a1a, f32x16& a1b) {
  bf16x8 af0 = *(const bf16x8*)(afb + 0 * 512 + lane8);
  bf16x8 af1 = *(const bf16x8*)(afb + 1 * 512 + lane8);
  a1a = mfma_bf16(af0, bfr[0], ZERO);
  a1b = mfma_bf16(af1, bfr[1], ZERO);
#pragma unroll
  for (int ks = 1; ks < 4; ++ks) {
    bf16x8 afa = *(const bf16x8*)(afb + (2 * ks) * 512 + lane8);
    bf16x8 afc = *(const bf16x8*)(afb + (2 * ks + 1) * 512 + lane8);
    a1a = mfma_bf16(afa, bfr[2 * ks], a1a);
    a1b = mfma_bf16(afc, bfr[2 * ks + 1], a1b);
  }
  bf16x8 af8 = *(const bf16x8*)(afb + 8 * 512 + lane8);
  a1a = mfma_bf16(af8, bfr[8], a1a);
}

// GEMM2: 16 MFMA on 8 independent accumulators (chunk's wf stage)
__device__ __forceinline__ void gemm2(const u16* wfb, int lane8,
                                      bf16x8 fA, bf16x8 fB, f32x16* acc2) {
#pragma unroll
  for (int ct = 0; ct < 8; ++ct) {
    bf16x8 wf = *(const bf16x8*)(wfb + ct * 512 + lane8);
    acc2[ct] = mfma_bf16(fA, wf, acc2[ct]);
  }
#pragma unroll
  for (int ct = 0; ct < 8; ++ct) {
    bf16x8 wf = *(const bf16x8*)(wfb + 4096 + ct * 512 + lane8);
    acc2[ct] = mfma_bf16(fB, wf, acc2[ct]);
  }
}

// SiLU + pack + permlane exchange -> next GEMM2 A-op frags
__device__ __forceinline__ void silupack(const f32x16& a1a, const f32x16& a1b,
                                         bf16x8& fragA, bf16x8& fragB) {
  unsigned d[8];
#pragma unroll
  for (int q = 0; q < 4; ++q) {
    float s0 = silu(a1a[4 * q + 0] + a1b[4 * q + 0]);
    float s1 = silu(a1a[4 * q + 1] + a1b[4 * q + 1]);
    float s2 = silu(a1a[4 * q + 2] + a1b[4 * q + 2]);
    float s3 = silu(a1a[4 * q + 3] + a1b[4 * q + 3]);
    d[2 * q]     = pk2f(s0, s1);
    d[2 * q + 1] = pk2f(s2, s3);
  }
  unsigned e0 = d[0], e1 = d[2];
  unsigned e2 = d[1], e3 = d[3];
  unsigned e4 = d[4], e5 = d[6];
  unsigned e6 = d[5], e7 = d[7];
  asm("v_permlane32_swap_b32 %0, %1" : "+v"(e0), "+v"(e1));
  asm("v_permlane32_swap_b32 %0, %1" : "+v"(e2), "+v"(e3));
  asm("v_permlane32_swap_b32 %0, %1" : "+v"(e4), "+v"(e5));
  asm("v_permlane32_swap_b32 %0, %1" : "+v"(e6), "+v"(e7));
  uint4 fav, fbv;
  fav.x = e0; fav.y = e2; fav.z = e1; fav.w = e3;
  fbv.x = e4; fbv.y = e6; fbv.z = e5; fbv.w = e7;
  fragA = __builtin_bit_cast(bf16x8, fav);   // k = ch*32 + 0..15
  fragB = __builtin_bit_cast(bf16x8, fbv);   // k = ch*32 + 16..31
}

// ------------------------------ main kernel --------------------------------
// 256 blocks x 512 thr (8 waves, 1 block/CU). Wave w owns rows [w*32,w*32+32)
// of the block's 256 rows. NSTAGE=6 LDS pipeline (153.6 KB), prefetch
// distance 3, barrier+vmcnt at EVEN chunks only. ANTI-PHASE groups:
//   waves 0-3 (A): [gemm1(ch); gemm2(ch-1); silupack(ch)]
//   waves 4-7 (B): [silupack(ch-1); gemm1(ch); gemm2(ch-1)]  (carry a1 regs)
// SIMD k hosts waves {k, k+4}: one issues the 25-MFMA cluster while the
// other issues silu VALU -> matrix/VALU overlap by construction.
__global__ __launch_bounds__(512, 2) void k_main(
    const u16* __restrict__ B1FS, const u16* __restrict__ B1FB,
    const u16* __restrict__ W2F,
    const float* __restrict__ mask, const float* __restrict__ depth,
    const float* __restrict__ cosx, const float* __restrict__ cosy,
    const float* __restrict__ bias2, float* __restrict__ out)
{
  __shared__ __align__(16) u16 sbuf[NSTAGE * STAGE_U16];   // 153600 B LDS
  float* stg = (float*)sbuf;                               // staging overlay

  const int tid = threadIdx.x;
  const int w = tid >> 6;            // 0..7
  const int lane = tid & 63;
  const int lane8 = lane * 8;
  const int l31 = lane & 31;
  const int lhi = lane >> 5;
  const bool gA = (w < 4);           // anti-phase group (SIMD k: waves k, k+4)
  // XCD-bijective swizzle: XCD x serves bswz in [32x,32x+32) -> 2 batches/XCD
  const int bswz = (blockIdx.x & 7) * 32 + (blockIdx.x >> 3);
  const int r0 = bswz * 256;
  const int b = r0 >> 12;
  const int oy0 = (r0 >> 6) & 63;   // multiple of 4

  // ---- stage tables: cosx[b] 2048f | cosy[b] 8 h-rows x16f | mask,depth 8 rows ----
  {
    const float4* cx4 = (const float4*)(cosx + (size_t)b * 2048);
    ((float4*)stg)[tid] = cx4[tid];                        // 512 x 16B
    if (tid < 128)
      stg[2048 + tid] = cosy[((size_t)b * 16 + (tid >> 3)) * 128 + 2 * oy0 + (tid & 7)];
    if (tid < 256) {
      ((float4*)(stg + 2176))[tid] = ((const float4*)(mask  + ((size_t)b * 128 + 2 * oy0) * 128))[tid];
      ((float4*)(stg + 3200))[tid] = ((const float4*)(depth + ((size_t)b * 128 + 2 * oy0) * 128))[tid];
    }
  }
  __syncthreads();

  // ---- build this lane's 9 GEMM1 B-op frags directly in registers ----
  // k=136 carries 1.0 so the bias column lands as +bias1[n].
  bf16x8 bfr[9];
  {
    const int r = w * 32 + l31;        // 0..255 block-local row
    const int oyl = r >> 6, ox = r & 63;
    float m[4], dd[4];
#pragma unroll
    for (int j = 0; j < 4; ++j) {
      int sy = j >> 1, sx = j & 1;
      float mv = stg[2176 + (2 * oyl + sy) * 128 + 2 * ox + sx];
      m[j] = mv;
      dd[j] = stg[3200 + (2 * oyl + sy) * 128 + 2 * ox + sx] * mv;
    }
#pragma unroll
    for (int ks = 0; ks < 9; ++ks) {
      const int k0 = ks * 16 + lhi * 8;
      unsigned dwords[4];
#pragma unroll
      for (int h = 0; h < 4; ++h) {
        float v[2];
#pragma unroll
        for (int p = 0; p < 2; ++p) {
          const int k = k0 + 2 * h + p;
          float vv;
          if (k < 64) {
            const int f = k >> 2, j = k & 3;
            vv = m[j] * stg[f * 128 + 2 * ox + (j & 1)];
          } else if (k < 128) {
            const int kk = k - 64, f = kk >> 2, j = kk & 3;
            vv = m[j] * stg[2048 + f * 8 + 2 * oyl + (j >> 1)];
          } else if (k < 132) {
            vv = m[k - 128];
          } else if (k < 136) {
            vv = dd[k - 132];
          } else if (k == 136) {
            vv = 1.0f;               // bias passthrough
          } else {
            vv = 0.f;
          }
          v[p] = vv;
        }
        dwords[h] = pk2(v[0], v[1]);
      }
      uint4 u; u.x = dwords[0]; u.y = dwords[1]; u.z = dwords[2]; u.w = dwords[3];
      bfr[ks] = __builtin_bit_cast(bf16x8, u);
    }
  }
  __syncthreads();   // all stg reads done before DMA overwrites sbuf

  f32x16 acc2[8];
#pragma unroll
  for (int c = 0; c < 8; ++c)
#pragma unroll
    for (int i = 0; i < 16; ++i) acc2[c][i] = 0.f;

  f32x16 ZERO;       // loop-invariant GEMM1 C-input
#pragma unroll
  for (int i = 0; i < 16; ++i) ZERO[i] = 0.f;

  // per-wave DMA slice: af frag w (B1FS; wave 7 also ks=8 from B1FB),
  // wf frags {9+w, 17+w} -> waves 0-6: 3 loads/prefetch, wave 7: 4
  const u16* apre_s = B1FS + lane8;                        // +4096/ch
  const u16* apre_b = B1FB + (size_t)b * 16384 + lane8;    // +512/ch
  const u16* wpre   = W2F + lane8;                         // +8192/ch

  auto prefetchP = [&](u16* dst) {   // issues NEXT sequential chunk
    gl_lds16(apre_s + w * 512, dst + w * 512);
    if (w == 7) gl_lds16(apre_b, dst + 8 * 512);
    gl_lds16(wpre + w * 512, dst + (9 + w) * 512);
    gl_lds16(wpre + (8 + w) * 512, dst + (17 + w) * 512);
    apre_s += 4096; apre_b += 512; wpre += 8192;
  };

  prefetchP(sbuf);                   // chunk 0 -> stage 0
  prefetchP(sbuf + STAGE_U16);       // chunk 1 -> stage 1
  prefetchP(sbuf + 2 * STAGE_U16);   // chunk 2 -> stage 2

  bf16x8 fragA, fragB;
  f32x16 pa, pb;                     // group-B carried GEMM1 outputs

  // ---- iteration 0 (even; peeled: no GEMM2 yet) ----
  {
    if (w == 7) asm volatile("s_waitcnt vmcnt(4)" ::: "memory");
    else        asm volatile("s_waitcnt vmcnt(3)" ::: "memory");
    __builtin_amdgcn_s_barrier();
    asm volatile("" ::: "memory");
    __builtin_amdgcn_sched_barrier(0);
    prefetchP(sbuf + 3 * STAGE_U16);                 // chunk 3 -> stage 3

    f32x16 a1a, a1b;
    __builtin_amdgcn_s_setprio(1);
    gemm1(sbuf, bfr, lane8, ZERO, a1a, a1b);
    __builtin_amdgcn_s_setprio(0);
    if (gA) {
      silupack(a1a, a1b, fragA, fragB);
    } else {
      pa = a1a; pb = a1b;            // defer silu to next iteration's top
    }
  }

  int st = 1;                        // stage of current chunk ch
  int stw = 4;                       // stage of chunk ch+3
  for (int ch = 1; ch < 32; ++ch) {
    if (!(ch & 1)) {                 // even: sync point for the next 2 iters
      if (ch == 30) asm volatile("s_waitcnt vmcnt(0)" ::: "memory");
      else if (w == 7) asm volatile("s_waitcnt vmcnt(4)" ::: "memory");
      else             asm volatile("s_waitcnt vmcnt(3)" ::: "memory");
      __builtin_amdgcn_s_barrier();
      asm volatile("" ::: "memory");
      __builtin_amdgcn_sched_barrier(0);
    }
    if (ch + 3 < 32) prefetchP(sbuf + stw * STAGE_U16);
    stw = (stw + 1 == NSTAGE) ? 0 : stw + 1;

    const u16* afb  = sbuf + st * STAGE_U16;                       // stage ch
    const int  stp  = (st == 0) ? NSTAGE - 1 : st - 1;             // stage ch-1
    const u16* wfbp = sbuf + stp * STAGE_U16 + 4608;

    if (gA) {
      // A: MFMA cluster first, then silu
      f32x16 a1a, a1b;
      __builtin_amdgcn_s_setprio(1);
      gemm1(afb, bfr, lane8, ZERO, a1a, a1b);      // GEMM1(ch)
      gemm2(wfbp, lane8, fragA, fragB, acc2);      // GEMM2(ch-1)
      __builtin_amdgcn_s_setprio(0);
      silupack(a1a, a1b, fragA, fragB);            // frags for GEMM2(ch)
    } else {
      // B: silu of carried GEMM1(ch-1) first, then MFMA cluster
      silupack(pa, pb, fragA, fragB);              // frags(ch-1)
      f32x16 a1a, a1b;
      __builtin_amdgcn_s_setprio(1);
      gemm1(afb, bfr, lane8, ZERO, a1a, a1b);      // GEMM1(ch)
      gemm2(wfbp, lane8, fragA, fragB, acc2);      // GEMM2(ch-1)
      __builtin_amdgcn_s_setprio(0);
      pa = a1a; pb = a1b;
    }
    st = (st + 1 == NSTAGE) ? 0 : st + 1;
  }

  // ---- tail: GEMM2(31); chunk 31 lives in stage 31%6 == 1 ----
  if (!gA) silupack(pa, pb, fragA, fragB);         // frags(31) for group B
  gemm2(sbuf + 1 * STAGE_U16 + 4608, lane8, fragA, fragB, acc2);

  // ---- epilogue: out[b][n2][oy][ox] = acc2 + bias2, float4 along ox ----
#pragma unroll
  for (int ct = 0; ct < 8; ++ct) {
    const int n2 = ct * 32 + l31;
    const float b2 = bias2[n2];
    float* ob = out + ((size_t)b * 256 + n2) * 4096;
#pragma unroll
    for (int q = 0; q < 4; ++q) {
      const int rl = w * 32 + 8 * q + 4 * lhi;   // block-local rows rl..rl+3
      const int oy = oy0 + (rl >> 6);
      const int ox = rl & 63;
      f32x4 v;
      v[0] = acc2[ct][4 * q + 0] + b2;
      v[1] = acc2[ct][4 * q + 1] + b2;
      v[2] = acc2[ct][4 * q + 2] + b2;
      v[3] = acc2[ct][4 * q + 3] + b2;
      *(f32x4*)(ob + oy * 64 + ox) = v;
    }
  }
}

// ------------------------------- launcher ----------------------------------

extern "C" void kernel_launch(void* const* d_in, const int* in_sizes, int n_in,
                              void* d_out, int out_size, void* d_ws, size_t ws_size,
                              hipStream_t stream) {
  const float* pos     = (const float*)d_in[0];
  const float* gestalt = (const float*)d_in[1];
  const float* mask    = (const float*)d_in[2];
  const float* depth   = (const float*)d_in[3];
  const float* w1      = (const float*)d_in[4];
  const float* bias1   = (const float*)d_in[5];
  const float* w2      = (const float*)d_in[6];
  const float* bias2   = (const float*)d_in[7];
  float* out = (float*)d_out;

  // workspace: cosx 128K | cosy 128K | B1FS 256K | B1FB 512K | W2F 512K
  const size_t NEED = 131072u + 131072u + 262144u + 524288u + 524288u;
  if (ws_size < NEED) {
    fprintf(stderr, "[kernel] ws_size=%zu < needed %zu — skipping launches\n",
            ws_size, NEED);
    return;
  }
  char* ws = (char*)d_ws;
  float* cosx = (float*)(ws);
  float* cosy = (float*)(ws + 131072);
  u16*   B1FS = (u16*)(ws + 262144);
  u16*   B1FB = (u16*)(ws + 262144 + 262144);
  u16*   W2F  = (u16*)(ws + 262144 + 262144 + 524288);

  k_pre<<<640, 256, 0, stream>>>(pos, gestalt, w1, w2, bias1, cosx, cosy,
                                 B1FS, B1FB, W2F);
  k_main<<<256, 512, 0, stream>>>(B1FS, B1FB, W2F, mask, depth, cosx, cosy,
                                  bias2, out);
}

// Round 12
// 149.520 us; speedup vs baseline: 1.0314x; 1.0314x over previous
//
#include <hip/hip_runtime.h>
#include <cstdio>

// ---------------------------------------------------------------------------
// MemoryEfficientRGBDecoderStem — algebraic reduction + fused bf16 MFMA.
//   GEMM1 K collapses 1156 -> 137 (pad 144): gestalt spatially constant
//   (per-batch Wg), cos embeddings separable in h/w, bias1 folded into the
//   k=136 column (input-side frag carries 1.0 there).
//   FINAL = R12 verbatim (best verified: 149.85 / 150.69 µs total, k_main
//   67.1-67.7 µs, absmax 0.015625).
//   R12 = 8-wave 256-row block, NSTAGE=6 LDS pipeline, barrier+counted
//   vmcnt every 2nd chunk, ANTI-PHASE wave groups (SIMD k hosts waves
//   {k,k+4}: one issues the 25-MFMA cluster while the partner issues silu
//   VALU), B1FS/B1FB dedup (shared k<128 repack + per-batch ks=8 frag),
//   XCD-bijective block swizzle.
//   Session ledger: R13 af-via-VMEM regressed (vmcnt-stream mixing drains
//   the DMA pipeline). R14/R15 doubled-tile (1 wave/SIMD, ~460 live regs)
//   failed correctness/container — suspected regalloc pathology; the
//   LDS-convoy halving theory (200->100 ds_read_b128/CU/step) remains the
//   untested lever for a future session with resource-usage preflight.
//   R17 4-batched k_pre: neutral-to-negative -> reverted; the ~83 µs
//   non-k_main residue is k_pre latency floor + harness overhead.
// ---------------------------------------------------------------------------

#define NFREQ 16
#define BB 16
#define G 256
#define KIN 1156
#define K1 144
#define STAGE_U16 12800   // 25600 B per stage: af 9216 B + wf 16384 B
#define NSTAGE 6

typedef unsigned short u16;
using bf16x8 = __bf16 __attribute__((ext_vector_type(8)));
using f32x16 = float __attribute__((ext_vector_type(16)));
using f32x4  = float __attribute__((ext_vector_type(4)));

__device__ __forceinline__ u16 f2bf(float f) {          // RNE (for weights)
  unsigned u = __float_as_uint(f);
  u += 0x7fffu + ((u >> 16) & 1u);
  return (u16)(u >> 16);
}
__device__ __forceinline__ unsigned pk2(float a, float b) {  // RNE pair
  return (unsigned)f2bf(a) | ((unsigned)f2bf(b) << 16);
}
// fast pair pack, round-half-up: 2x v_add + v_perm_b32
__device__ __forceinline__ unsigned pk2f(float a, float b) {
  unsigned ua = __float_as_uint(a) + 0x8000u;
  unsigned ub = __float_as_uint(b) + 0x8000u;
  return __builtin_amdgcn_perm(ub, ua, 0x07060302u);  // {ub.hi16, ua.hi16}
}
// fast silu: v_mul + v_exp_f32 + v_add + v_rcp_f32 + v_mul
__device__ __forceinline__ float silu(float h) {
  float e = __builtin_amdgcn_exp2f(h * -1.44269504088896f);
  return h * __builtin_amdgcn_rcpf(1.f + e);
}
// async global->LDS DMA: per-lane g addr, wave-uniform LDS base; lane i -> l + 16*i
__device__ __forceinline__ void gl_lds16(const u16* g, u16* l) {
  __builtin_amdgcn_global_load_lds(
      (const __attribute__((address_space(1))) void*)g,
      (__attribute__((address_space(3))) void*)l, 16, 0, 0);
}

// --------------------------- fused prologue --------------------------------
// blocks [0,1024): B1FS/B1FB build | [1024,1152): W2F pack | [1152,1408): cos
__global__ void k_pre(const float* __restrict__ pos,
                      const float* __restrict__ gestalt,
                      const float* __restrict__ w1,
                      const float* __restrict__ w2,
                      const float* __restrict__ bias1,
                      float* __restrict__ cosx, float* __restrict__ cosy,
                      u16* __restrict__ B1FS, u16* __restrict__ B1FB,
                      u16* __restrict__ W2F) {
  const int bid = blockIdx.x;
  const int t = threadIdx.x;

  if (bid < 1024) {
    // ---- per-batch reduced W1, frag-contiguous bf16 ----
    __shared__ float w1row[KIN];
    __shared__ float gestT[G * 17];   // [c][bb], pitch 17: conflict-free R/W
    __shared__ float psum[256];
    __shared__ float wg[64];
    const int n = bid;
    const float b1v = bias1[n];       // folded into k=136 column
#pragma unroll
    for (int i = t; i < KIN; i += 256) w1row[i] = w1[(size_t)n * KIN + i];
#pragma unroll
    for (int i = t; i < BB * G; i += 256) {
      int bb = i >> 8, c = i & 255;
      gestT[c * 17 + bb] = gestalt[i];
    }
    __syncthreads();
    {
      // Wg[bb][j] = sum_c gestalt[bb][c]*w1[n][4c+j]; t = q*64 + j*16 + bb
      int bb = t & 15, j = (t >> 4) & 3, q = t >> 6;
      float acc = 0.f;
#pragma unroll 8
      for (int c = q * 64; c < q * 64 + 64; ++c)
        acc += gestT[c * 17 + bb] * w1row[4 * c + j];
      psum[t] = acc;
    }
    __syncthreads();
    if (t < 64) {
      int bb = t >> 2, j = t & 3;
      wg[t] = psum[j * 16 + bb] + psum[64 + j * 16 + bb] +
              psum[128 + j * 16 + bb] + psum[192 + j * 16 + bb];
    }
    __syncthreads();
    const int ch = n >> 5, l31n = n & 31;
    // 48 chunks: {kc 0..15, bb=0 shared} -> B1FS ; {kc 16,17 x bb 0..15} -> B1FB
    if (t < 48) {
      int bb, kc;
      if (t < 16) { bb = 0; kc = t; }
      else        { bb = (t - 16) >> 1; kc = 16 + ((t - 16) & 1); }
      int k0 = kc * 8;
      float v[8];
#pragma unroll
      for (int i = 0; i < 8; ++i) {
        int k = k0 + i;
        float vv;
        if (k < 64)       vv = w1row[1024 + 8 * (k >> 2) + (k & 3)];
        else if (k < 128) { int kk = k - 64; vv = w1row[1024 + 8 * (kk >> 2) + 4 + (kk & 3)]; }
        else if (k < 132) vv = wg[bb * 4 + (k - 128)];
        else if (k < 136) vv = w1row[1152 + (k - 132)];
        else if (k == 136) vv = b1v;   // bias column
        else              vv = 0.f;
        v[i] = vv;
      }
      uint4 u;
      u.x = pk2(v[0], v[1]); u.y = pk2(v[2], v[3]);
      u.z = pk2(v[4], v[5]); u.w = pk2(v[6], v[7]);
      if (kc < 16) {
        size_t idx0 = (((size_t)ch * 8 + (kc >> 1)) * 64 + (kc & 1) * 32 + l31n) * 8;
        *(uint4*)(B1FS + idx0) = u;
      } else {
        size_t idx0 = (((size_t)bb * 32 + ch) * 64 + (kc - 16) * 32 + l31n) * 8;
        *(uint4*)(B1FB + idx0) = u;
      }
    }
  } else if (bid < 1152) {
    // ---- W2F: frag-contiguous bf16; 8 u16 per thread, uint4 store ----
    int e8 = (bid - 1024) * 256 + t;    // 0..32767
    int lane = e8 & 63;
    int ct   = (e8 >> 6) & 7;
    int kc   = e8 >> 9;
    int n2 = ct * 32 + (lane & 31);
    int k2 = kc * 16 + (lane >> 5) * 8;
    const float* src = w2 + (size_t)n2 * 1024 + k2;
    uint4 u;
    u.x = pk2(src[0], src[1]); u.y = pk2(src[2], src[3]);
    u.z = pk2(src[4], src[5]); u.w = pk2(src[6], src[7]);
    *(uint4*)(W2F + (size_t)e8 * 8) = u;
  } else {
    // ---- cos tables (exact fp32 op-order of reference) ----
    int idx = (bid - 1152) * 256 + t;   // 0..65535
    int table = idx >> 15;
    int rem = idx & 32767;
    int b = rem >> 11;
    int f = (rem >> 7) & 15;
    int c = rem & 127;
    float p0 = pos[b * 4 + 0];
    float p1 = pos[b * 4 + 1];
    float p3 = pos[b * 4 + 3];
    float x = fminf(fmaxf(p0, -1.f), 1.f);
    float y = fminf(fmaxf(p1, -1.f), 1.f);
    float stdv = 0.1f / fminf(fmaxf(p3, 0.0078125f), 0.5f);  // min_std = 1/128
    const float half_pi = 1.57079632679489661923f;
    float g = ((float)c / 127.0f) * 2.0f - 1.0f;
    float ng = (table == 0) ? ((g - x) * stdv) * half_pi     // std_x = std (W/H=1)
                            : ((g - y) * stdv) * half_pi;
    float freq = (float)(1 << f);
    float val = cosf(ng * freq);
    if (table == 0) cosx[(b * NFREQ + f) * 128 + c] = val;
    else            cosy[(b * NFREQ + f) * 128 + c] = val;
  }
}

// ----------------------- main-kernel compute helpers -----------------------

__device__ __forceinline__ f32x16 mfma_bf16(bf16x8 a, bf16x8 b, f32x16 c) {
  return __builtin_amdgcn_mfma_f32_32x32x16_bf16(a, b, c, 0, 0, 0);
}

// GEMM1: 9 MFMA, two independent chains, C-input = hoisted ZERO
__device__ __forceinline__ void gemm1(const u16* afb, const bf16x8* bfr, int lane8,
                                      const f32x16& ZERO, f32x16& a1a, f32x16& a1b) {
  bf16x8 af0 = *(const bf16x8*)(afb + 0 * 512 + lane8);
  bf16x8 af1 = *(const bf16x8*)(afb + 1 * 512 + lane8);
  a1a = mfma_bf16(af0, bfr[0], ZERO);
  a1b = mfma_bf16(af1, bfr[1], ZERO);
#pragma unroll
  for (int ks = 1; ks < 4; ++ks) {
    bf16x8 afa = *(const bf16x8*)(afb + (2 * ks) * 512 + lane8);
    bf16x8 afc = *(const bf16x8*)(afb + (2 * ks + 1) * 512 + lane8);
    a1a = mfma_bf16(afa, bfr[2 * ks], a1a);
    a1b = mfma_bf16(afc, bfr[2 * ks + 1], a1b);
  }
  bf16x8 af8 = *(const bf16x8*)(afb + 8 * 512 + lane8);
  a1a = mfma_bf16(af8, bfr[8], a1a);
}

// GEMM2: 16 MFMA on 8 independent accumulators (chunk's wf stage)
__device__ __forceinline__ void gemm2(const u16* wfb, int lane8,
                                      bf16x8 fA, bf16x8 fB, f32x16* acc2) {
#pragma unroll
  for (int ct = 0; ct < 8; ++ct) {
    bf16x8 wf = *(const bf16x8*)(wfb + ct * 512 + lane8);
    acc2[ct] = mfma_bf16(fA, wf, acc2[ct]);
  }
#pragma unroll
  for (int ct = 0; ct < 8; ++ct) {
    bf16x8 wf = *(const bf16x8*)(wfb + 4096 + ct * 512 + lane8);
    acc2[ct] = mfma_bf16(fB, wf, acc2[ct]);
  }
}

// SiLU + pack + permlane exchange -> next GEMM2 A-op frags
__device__ __forceinline__ void silupack(const f32x16& a1a, const f32x16& a1b,
                                         bf16x8& fragA, bf16x8& fragB) {
  unsigned d[8];
#pragma unroll
  for (int q = 0; q < 4; ++q) {
    float s0 = silu(a1a[4 * q + 0] + a1b[4 * q + 0]);
    float s1 = silu(a1a[4 * q + 1] + a1b[4 * q + 1]);
    float s2 = silu(a1a[4 * q + 2] + a1b[4 * q + 2]);
    float s3 = silu(a1a[4 * q + 3] + a1b[4 * q + 3]);
    d[2 * q]     = pk2f(s0, s1);
    d[2 * q + 1] = pk2f(s2, s3);
  }
  unsigned e0 = d[0], e1 = d[2];
  unsigned e2 = d[1], e3 = d[3];
  unsigned e4 = d[4], e5 = d[6];
  unsigned e6 = d[5], e7 = d[7];
  asm("v_permlane32_swap_b32 %0, %1" : "+v"(e0), "+v"(e1));
  asm("v_permlane32_swap_b32 %0, %1" : "+v"(e2), "+v"(e3));
  asm("v_permlane32_swap_b32 %0, %1" : "+v"(e4), "+v"(e5));
  asm("v_permlane32_swap_b32 %0, %1" : "+v"(e6), "+v"(e7));
  uint4 fav, fbv;
  fav.x = e0; fav.y = e2; fav.z = e1; fav.w = e3;
  fbv.x = e4; fbv.y = e6; fbv.z = e5; fbv.w = e7;
  fragA = __builtin_bit_cast(bf16x8, fav);   // k = ch*32 + 0..15
  fragB = __builtin_bit_cast(bf16x8, fbv);   // k = ch*32 + 16..31
}

// ------------------------------ main kernel --------------------------------
// 256 blocks x 512 thr (8 waves, 1 block/CU). Wave w owns rows [w*32,w*32+32)
// of the block's 256 rows. NSTAGE=6 LDS pipeline (153.6 KB), prefetch
// distance 3, barrier+vmcnt at EVEN chunks only. ANTI-PHASE groups:
//   waves 0-3 (A): [gemm1(ch); gemm2(ch-1); silupack(ch)]
//   waves 4-7 (B): [silupack(ch-1); gemm1(ch); gemm2(ch-1)]  (carry a1 regs)
// SIMD k hosts waves {k, k+4}: one issues the 25-MFMA cluster while the
// other issues silu VALU -> matrix/VALU overlap by construction.
__global__ __launch_bounds__(512, 2) void k_main(
    const u16* __restrict__ B1FS, const u16* __restrict__ B1FB,
    const u16* __restrict__ W2F,
    const float* __restrict__ mask, const float* __restrict__ depth,
    const float* __restrict__ cosx, const float* __restrict__ cosy,
    const float* __restrict__ bias2, float* __restrict__ out)
{
  __shared__ __align__(16) u16 sbuf[NSTAGE * STAGE_U16];   // 153600 B LDS
  float* stg = (float*)sbuf;                               // staging overlay

  const int tid = threadIdx.x;
  const int w = tid >> 6;            // 0..7
  const int lane = tid & 63;
  const int lane8 = lane * 8;
  const int l31 = lane & 31;
  const int lhi = lane >> 5;
  const bool gA = (w < 4);           // anti-phase group (SIMD k: waves k, k+4)
  // XCD-bijective swizzle: XCD x serves bswz in [32x,32x+32) -> 2 batches/XCD
  const int bswz = (blockIdx.x & 7) * 32 + (blockIdx.x >> 3);
  const int r0 = bswz * 256;
  const int b = r0 >> 12;
  const int oy0 = (r0 >> 6) & 63;   // multiple of 4

  // ---- stage tables: cosx[b] 2048f | cosy[b] 8 h-rows x16f | mask,depth 8 rows ----
  {
    const float4* cx4 = (const float4*)(cosx + (size_t)b * 2048);
    ((float4*)stg)[tid] = cx4[tid];                        // 512 x 16B
    if (tid < 128)
      stg[2048 + tid] = cosy[((size_t)b * 16 + (tid >> 3)) * 128 + 2 * oy0 + (tid & 7)];
    if (tid < 256) {
      ((float4*)(stg + 2176))[tid] = ((const float4*)(mask  + ((size_t)b * 128 + 2 * oy0) * 128))[tid];
      ((float4*)(stg + 3200))[tid] = ((const float4*)(depth + ((size_t)b * 128 + 2 * oy0) * 128))[tid];
    }
  }
  __syncthreads();

  // ---- build this lane's 9 GEMM1 B-op frags directly in registers ----
  // k=136 carries 1.0 so the bias column lands as +bias1[n].
  bf16x8 bfr[9];
  {
    const int r = w * 32 + l31;        // 0..255 block-local row
    const int oyl = r >> 6, ox = r & 63;
    float m[4], dd[4];
#pragma unroll
    for (int j = 0; j < 4; ++j) {
      int sy = j >> 1, sx = j & 1;
      float mv = stg[2176 + (2 * oyl + sy) * 128 + 2 * ox + sx];
      m[j] = mv;
      dd[j] = stg[3200 + (2 * oyl + sy) * 128 + 2 * ox + sx] * mv;
    }
#pragma unroll
    for (int ks = 0; ks < 9; ++ks) {
      const int k0 = ks * 16 + lhi * 8;
      unsigned dwords[4];
#pragma unroll
      for (int h = 0; h < 4; ++h) {
        float v[2];
#pragma unroll
        for (int p = 0; p < 2; ++p) {
          const int k = k0 + 2 * h + p;
          float vv;
          if (k < 64) {
            const int f = k >> 2, j = k & 3;
            vv = m[j] * stg[f * 128 + 2 * ox + (j & 1)];
          } else if (k < 128) {
            const int kk = k - 64, f = kk >> 2, j = kk & 3;
            vv = m[j] * stg[2048 + f * 8 + 2 * oyl + (j >> 1)];
          } else if (k < 132) {
            vv = m[k - 128];
          } else if (k < 136) {
            vv = dd[k - 132];
          } else if (k == 136) {
            vv = 1.0f;               // bias passthrough
          } else {
            vv = 0.f;
          }
          v[p] = vv;
        }
        dwords[h] = pk2(v[0], v[1]);
      }
      uint4 u; u.x = dwords[0]; u.y = dwords[1]; u.z = dwords[2]; u.w = dwords[3];
      bfr[ks] = __builtin_bit_cast(bf16x8, u);
    }
  }
  __syncthreads();   // all stg reads done before DMA overwrites sbuf

  f32x16 acc2[8];
#pragma unroll
  for (int c = 0; c < 8; ++c)
#pragma unroll
    for (int i = 0; i < 16; ++i) acc2[c][i] = 0.f;

  f32x16 ZERO;       // loop-invariant GEMM1 C-input
#pragma unroll
  for (int i = 0; i < 16; ++i) ZERO[i] = 0.f;

  // per-wave DMA slice: af frag w (B1FS; wave 7 also ks=8 from B1FB),
  // wf frags {9+w, 17+w} -> waves 0-6: 3 loads/prefetch, wave 7: 4
  const u16* apre_s = B1FS + lane8;                        // +4096/ch
  const u16* apre_b = B1FB + (size_t)b * 16384 + lane8;    // +512/ch
  const u16* wpre   = W2F + lane8;                         // +8192/ch

  auto prefetchP = [&](u16* dst) {   // issues NEXT sequential chunk
    gl_lds16(apre_s + w * 512, dst + w * 512);
    if (w == 7) gl_lds16(apre_b, dst + 8 * 512);
    gl_lds16(wpre + w * 512, dst + (9 + w) * 512);
    gl_lds16(wpre + (8 + w) * 512, dst + (17 + w) * 512);
    apre_s += 4096; apre_b += 512; wpre += 8192;
  };

  prefetchP(sbuf);                   // chunk 0 -> stage 0
  prefetchP(sbuf + STAGE_U16);       // chunk 1 -> stage 1
  prefetchP(sbuf + 2 * STAGE_U16);   // chunk 2 -> stage 2

  bf16x8 fragA, fragB;
  f32x16 pa, pb;                     // group-B carried GEMM1 outputs

  // ---- iteration 0 (even; peeled: no GEMM2 yet) ----
  {
    if (w == 7) asm volatile("s_waitcnt vmcnt(4)" ::: "memory");
    else        asm volatile("s_waitcnt vmcnt(3)" ::: "memory");
    __builtin_amdgcn_s_barrier();
    asm volatile("" ::: "memory");
    __builtin_amdgcn_sched_barrier(0);
    prefetchP(sbuf + 3 * STAGE_U16);                 // chunk 3 -> stage 3

    f32x16 a1a, a1b;
    __builtin_amdgcn_s_setprio(1);
    gemm1(sbuf, bfr, lane8, ZERO, a1a, a1b);
    __builtin_amdgcn_s_setprio(0);
    if (gA) {
      silupack(a1a, a1b, fragA, fragB);
    } else {
      pa = a1a; pb = a1b;            // defer silu to next iteration's top
    }
  }

  int st = 1;                        // stage of current chunk ch
  int stw = 4;                       // stage of chunk ch+3
  for (int ch = 1; ch < 32; ++ch) {
    if (!(ch & 1)) {                 // even: sync point for the next 2 iters
      if (ch == 30) asm volatile("s_waitcnt vmcnt(0)" ::: "memory");
      else if (w == 7) asm volatile("s_waitcnt vmcnt(4)" ::: "memory");
      else             asm volatile("s_waitcnt vmcnt(3)" ::: "memory");
      __builtin_amdgcn_s_barrier();
      asm volatile("" ::: "memory");
      __builtin_amdgcn_sched_barrier(0);
    }
    if (ch + 3 < 32) prefetchP(sbuf + stw * STAGE_U16);
    stw = (stw + 1 == NSTAGE) ? 0 : stw + 1;

    const u16* afb  = sbuf + st * STAGE_U16;                       // stage ch
    const int  stp  = (st == 0) ? NSTAGE - 1 : st - 1;             // stage ch-1
    const u16* wfbp = sbuf + stp * STAGE_U16 + 4608;

    if (gA) {
      // A: MFMA cluster first, then silu
      f32x16 a1a, a1b;
      __builtin_amdgcn_s_setprio(1);
      gemm1(afb, bfr, lane8, ZERO, a1a, a1b);      // GEMM1(ch)
      gemm2(wfbp, lane8, fragA, fragB, acc2);      // GEMM2(ch-1)
      __builtin_amdgcn_s_setprio(0);
      silupack(a1a, a1b, fragA, fragB);            // frags for GEMM2(ch)
    } else {
      // B: silu of carried GEMM1(ch-1) first, then MFMA cluster
      silupack(pa, pb, fragA, fragB);              // frags(ch-1)
      f32x16 a1a, a1b;
      __builtin_amdgcn_s_setprio(1);
      gemm1(afb, bfr, lane8, ZERO, a1a, a1b);      // GEMM1(ch)
      gemm2(wfbp, lane8, fragA, fragB, acc2);      // GEMM2(ch-1)
      __builtin_amdgcn_s_setprio(0);
      pa = a1a; pb = a1b;
    }
    st = (st + 1 == NSTAGE) ? 0 : st + 1;
  }

  // ---- tail: GEMM2(31); chunk 31 lives in stage 31%6 == 1 ----
  if (!gA) silupack(pa, pb, fragA, fragB);         // frags(31) for group B
  gemm2(sbuf + 1 * STAGE_U16 + 4608, lane8, fragA, fragB, acc2);

  // ---- epilogue: out[b][n2][oy][ox] = acc2 + bias2, float4 along ox ----
#pragma unroll
  for (int ct = 0; ct < 8; ++ct) {
    const int n2 = ct * 32 + l31;
    const float b2 = bias2[n2];
    float* ob = out + ((size_t)b * 256 + n2) * 4096;
#pragma unroll
    for (int q = 0; q < 4; ++q) {
      const int rl = w * 32 + 8 * q + 4 * lhi;   // block-local rows rl..rl+3
      const int oy = oy0 + (rl >> 6);
      const int ox = rl & 63;
      f32x4 v;
      v[0] = acc2[ct][4 * q + 0] + b2;
      v[1] = acc2[ct][4 * q + 1] + b2;
      v[2] = acc2[ct][4 * q + 2] + b2;
      v[3] = acc2[ct][4 * q + 3] + b2;
      *(f32x4*)(ob + oy * 64 + ox) = v;
    }
  }
}

// ------------------------------- launcher ----------------------------------

extern "C" void kernel_launch(void* const* d_in, const int* in_sizes, int n_in,
                              void* d_out, int out_size, void* d_ws, size_t ws_size,
                              hipStream_t stream) {
  const float* pos     = (const float*)d_in[0];
  const float* gestalt = (const float*)d_in[1];
  const float* mask    = (const float*)d_in[2];
  const float* depth   = (const float*)d_in[3];
  const float* w1      = (const float*)d_in[4];
  const float* bias1   = (const float*)d_in[5];
  const float* w2      = (const float*)d_in[6];
  const float* bias2   = (const float*)d_in[7];
  float* out = (float*)d_out;

  // workspace: cosx 128K | cosy 128K | B1FS 256K | B1FB 512K | W2F 512K
  const size_t NEED = 131072u + 131072u + 262144u + 524288u + 524288u;
  if (ws_size < NEED) {
    fprintf(stderr, "[kernel] ws_size=%zu < needed %zu — skipping launches\n",
            ws_size, NEED);
    return;
  }
  char* ws = (char*)d_ws;
  float* cosx = (float*)(ws);
  float* cosy = (float*)(ws + 131072);
  u16*   B1FS = (u16*)(ws + 262144);
  u16*   B1FB = (u16*)(ws + 262144 + 262144);
  u16*   W2F  = (u16*)(ws + 262144 + 262144 + 524288);

  k_pre<<<1408, 256, 0, stream>>>(pos, gestalt, w1, w2, bias1, cosx, cosy,
                                  B1FS, B1FB, W2F);
  k_main<<<256, 512, 0, stream>>>(B1FS, B1FB, W2F, mask, depth, cosx, cosy,
                                  bias2, out);
}